// Round 1
// baseline (332.812 us; speedup 1.0000x reference)
//
#include <hip/hip_runtime.h>

typedef unsigned short u16;
typedef short bf16x8 __attribute__((ext_vector_type(8)));
typedef float f32x4 __attribute__((ext_vector_type(4)));

constexpr int Bb = 8, S = 1024, E = 1024, H = 16, D = 64;
constexpr int M = Bb * S;  // 8192

__device__ inline u16 f2bf(float f) {
  unsigned u = __builtin_bit_cast(unsigned, f);
  return (u16)((u + 0x7fffu + ((u >> 16) & 1u)) >> 16);
}

__device__ inline f32x4 mfma16(bf16x8 a, bf16x8 b, f32x4 c) {
  return __builtin_amdgcn_mfma_f32_16x16x32_bf16(a, b, c, 0, 0, 0);
}

__device__ inline void gld16(const u16* g, u16* l) {
  __builtin_amdgcn_global_load_lds(
      (const __attribute__((address_space(1))) void*)g,
      (__attribute__((address_space(3))) void*)l, 16, 0, 0);
}

// ---------------- cast fp32 -> bf16 ----------------
__global__ __launch_bounds__(256) void cast_bf16(const float* __restrict__ in,
                                                 u16* __restrict__ out, int n) {
  int i = (blockIdx.x * blockDim.x + threadIdx.x) * 4;
  if (i >= n) return;
  float4 v = *(const float4*)(in + i);
  u16 o[4] = {f2bf(v.x), f2bf(v.y), f2bf(v.z), f2bf(v.w)};
  *(uint2*)(out + i) = *(const uint2*)o;
}

// ---------------- GEMM: C = A(MxK) * Bm(NxK)^T + bias ----------------
// EPI: 0 = bf16 out, 1 = bf16 out + RoPE, 2 = f32 out
template <int EPI>
__global__ __launch_bounds__(256) void gemm_bt(const u16* __restrict__ A,
                                               const u16* __restrict__ Bm,
                                               const float* __restrict__ bias,
                                               void* __restrict__ Cout, int K) {
  constexpr int N = 1024;
  __shared__ u16 As[4 * 128 * 8];  // [kb][row][8]
  __shared__ u16 Bs[4 * 128 * 8];
  int bid = blockIdx.x;
  int mb = bid >> 3, nb = bid & 7;
  int m0 = mb * 128, n0 = nb * 128;
  int tid = threadIdx.x, lane = tid & 63, wid = tid >> 6;
  int wr = wid >> 1, wc = wid & 1;
  int fr = lane & 15, fq = lane >> 4;

  f32x4 acc[4][4] = {};
  const bf16x8* As8 = (const bf16x8*)As;
  const bf16x8* Bs8 = (const bf16x8*)Bs;

  for (int k0 = 0; k0 < K; k0 += 32) {
#pragma unroll
    for (int c2 = 0; c2 < 2; ++c2) {
      int chunk = wid * 2 + c2;
      int kb = chunk >> 1, rh = (chunk & 1) * 64;
      gld16(A + (size_t)(m0 + rh + lane) * K + k0 + kb * 8, &As[chunk * 512 + lane * 8]);
      gld16(Bm + (size_t)(n0 + rh + lane) * K + k0 + kb * 8, &Bs[chunk * 512 + lane * 8]);
    }
    __syncthreads();
    bf16x8 af[4], bfr[4];
#pragma unroll
    for (int m = 0; m < 4; ++m) af[m] = As8[fq * 128 + wr * 64 + m * 16 + fr];
#pragma unroll
    for (int n = 0; n < 4; ++n) bfr[n] = Bs8[fq * 128 + wc * 64 + n * 16 + fr];
#pragma unroll
    for (int m = 0; m < 4; ++m)
#pragma unroll
      for (int n = 0; n < 4; ++n) acc[m][n] = mfma16(af[m], bfr[n], acc[m][n]);
    __syncthreads();
  }

#pragma unroll
  for (int m = 0; m < 4; ++m) {
#pragma unroll
    for (int j = 0; j < 4; ++j) {
      int r = m0 + wr * 64 + m * 16 + fq * 4 + j;
      if (EPI == 1) {
        int s = r & (S - 1);
#pragma unroll
        for (int n = 0; n < 2; ++n) {
          int c = n0 + wc * 64 + n * 16 + fr;
          int d1 = c & 63;  // in [0,32)
          float x1 = acc[m][n][j] + bias[c];
          float x2 = acc[m][n + 2][j] + bias[c + 32];
          float invf = exp2f((float)d1 * (-13.287712379549449f / 32.f));
          float ang = (float)s * invf;
          float sn, cs;
          sincosf(ang, &sn, &cs);
          ((u16*)Cout)[(size_t)r * N + c] = f2bf(x1 * cs - x2 * sn);
          ((u16*)Cout)[(size_t)r * N + c + 32] = f2bf(x1 * sn + x2 * cs);
        }
      } else if (EPI == 0) {
#pragma unroll
        for (int n = 0; n < 4; ++n) {
          int c = n0 + wc * 64 + n * 16 + fr;
          ((u16*)Cout)[(size_t)r * N + c] = f2bf(acc[m][n][j] + bias[c]);
        }
      } else {
#pragma unroll
        for (int n = 0; n < 4; ++n) {
          int c = n0 + wc * 64 + n * 16 + fr;
          ((float*)Cout)[(size_t)r * N + c] = acc[m][n][j] + bias[c];
        }
      }
    }
  }
}

// ---------------- V transpose: (B,S,E) -> (B,H,D,S) ----------------
__global__ __launch_bounds__(256) void transpose_v(const u16* __restrict__ Vh,
                                                   u16* __restrict__ Vt) {
  __shared__ u16 t[64][80];
  int bid = blockIdx.x;  // B*H*16
  int s0 = (bid & 15) * 64;
  int bh = bid >> 4;
  int b = bh >> 4, h = bh & 15;
  int tid = threadIdx.x;
  {
    int sl = tid >> 2, d4 = (tid & 3) * 16;
    const uint4* src = (const uint4*)(Vh + (size_t)(b * S + s0 + sl) * E + h * 64 + d4);
    uint4 v0 = src[0], v1 = src[1];
    *(uint4*)&t[sl][d4] = v0;
    *(uint4*)&t[sl][d4 + 8] = v1;
  }
  __syncthreads();
  {
    int dl = tid >> 2, s4 = (tid & 3) * 16;
    u16 tmp[16];
#pragma unroll
    for (int e = 0; e < 16; ++e) tmp[e] = t[s4 + e][dl];
    u16* dst = Vt + (size_t)((b * H + h) * D + dl) * S + s0 + s4;
    *(uint4*)dst = *(const uint4*)tmp;
    *(uint4*)(dst + 8) = *(const uint4*)(tmp + 8);
  }
}

// ---------------- flash attention ----------------
__global__ __launch_bounds__(256) void attn_fwd(const u16* __restrict__ Qh,
                                                const u16* __restrict__ Kh,
                                                const u16* __restrict__ Vt,
                                                const int* __restrict__ mask,
                                                u16* __restrict__ X) {
  __shared__ u16 Ks[8 * 64 * 8];      // [dblk][key][8]
  __shared__ u16 Vs[8 * 64 * 8];      // [keyblk][d][8keys]
  __shared__ u16 Ps[4 * 8 * 16 * 8];  // [wave][keyblk][q][8]
  int bid = blockIdx.x;
  int qt = bid & 15;
  int bh = bid >> 4;
  int b = bh >> 4, h = bh & 15;
  int q0 = qt * 64;
  int tid = threadIdx.x, lane = tid & 63, wid = tid >> 6;
  int fr = lane & 15, fq = lane >> 4;

  bf16x8 aq[2];
  {
    int qrow = b * S + q0 + wid * 16 + fr;
    const u16* qp = Qh + (size_t)qrow * E + h * 64 + fq * 8;
    aq[0] = *(const bf16x8*)qp;
    aq[1] = *(const bf16x8*)(qp + 32);
  }
  f32x4 oacc[4] = {};
  float mrun[4], lrun[4];
#pragma unroll
  for (int j = 0; j < 4; ++j) {
    mrun[j] = -INFINITY;
    lrun[j] = 0.f;
  }
  const bf16x8* Ks8 = (const bf16x8*)Ks;
  const bf16x8* Vs8 = (const bf16x8*)Vs;
  const bf16x8* Ps8 = (const bf16x8*)Ps;
  size_t kbase = (size_t)(b * S) * E + h * 64;
  size_t vbase = (size_t)((b * H + h) * D) * S;
  const int* mrow = mask + b * S;

  for (int t = 0; t < 16; ++t) {
    int kv0 = t * 64;
#pragma unroll
    for (int c2 = 0; c2 < 2; ++c2) {
      int c = wid * 2 + c2;
      gld16(Kh + kbase + (size_t)(kv0 + lane) * E + c * 8, &Ks[c * 512 + lane * 8]);
      gld16(Vt + vbase + (size_t)lane * S + kv0 + c * 8, &Vs[c * 512 + lane * 8]);
    }
    __syncthreads();

    f32x4 sa[4];
#pragma unroll
    for (int jb = 0; jb < 4; ++jb) {
      f32x4 z = {};
#pragma unroll
      for (int kk = 0; kk < 2; ++kk)
        z = mfma16(aq[kk], Ks8[(kk * 4 + fq) * 64 + jb * 16 + fr], z);
      sa[jb] = z;
    }
    int mv[4];
#pragma unroll
    for (int jb = 0; jb < 4; ++jb) mv[jb] = mrow[kv0 + jb * 16 + fr];
#pragma unroll
    for (int jb = 0; jb < 4; ++jb)
#pragma unroll
      for (int j = 0; j < 4; ++j)
        sa[jb][j] = (mv[jb] == 0) ? -1e20f : sa[jb][j] * 0.125f;

    float fac[4];
#pragma unroll
    for (int j = 0; j < 4; ++j) {
      float mt = fmaxf(fmaxf(sa[0][j], sa[1][j]), fmaxf(sa[2][j], sa[3][j]));
#pragma unroll
      for (int off = 1; off < 16; off <<= 1) mt = fmaxf(mt, __shfl_xor(mt, off));
      float mnew = fmaxf(mrun[j], mt);
      fac[j] = __expf(mrun[j] - mnew);
      float pr = 0.f;
#pragma unroll
      for (int jb = 0; jb < 4; ++jb) {
        float p = __expf(sa[jb][j] - mnew);
        sa[jb][j] = p;
        pr += p;
      }
#pragma unroll
      for (int off = 1; off < 16; off <<= 1) pr += __shfl_xor(pr, off);
      lrun[j] = lrun[j] * fac[j] + pr;
      mrun[j] = mnew;
    }
#pragma unroll
    for (int db = 0; db < 4; ++db)
#pragma unroll
      for (int j = 0; j < 4; ++j) oacc[db][j] *= fac[j];

#pragma unroll
    for (int jb = 0; jb < 4; ++jb) {
      int kbp = jb * 2 + (fr >> 3);
      int idx = fr & 7;
#pragma unroll
      for (int j = 0; j < 4; ++j) {
        int qq = fq * 4 + j;
        Ps[((wid * 8 + kbp) * 16 + qq) * 8 + idx] = f2bf(sa[jb][j]);
      }
    }

#pragma unroll
    for (int kk2 = 0; kk2 < 2; ++kk2) {
      bf16x8 pa = Ps8[(wid * 8 + kk2 * 4 + fq) * 16 + fr];
#pragma unroll
      for (int db = 0; db < 4; ++db)
        oacc[db] = mfma16(pa, Vs8[(kk2 * 4 + fq) * 64 + db * 16 + fr], oacc[db]);
    }
    __syncthreads();
  }

#pragma unroll
  for (int db = 0; db < 4; ++db)
#pragma unroll
    for (int j = 0; j < 4; ++j) {
      int qq = q0 + wid * 16 + fq * 4 + j;
      float v = oacc[db][j] / lrun[j];
      X[(size_t)(b * S + qq) * E + h * 64 + db * 16 + fr] = f2bf(v);
    }
}

extern "C" void kernel_launch(void* const* d_in, const int* in_sizes, int n_in,
                              void* d_out, int out_size, void* d_ws, size_t ws_size,
                              hipStream_t stream) {
  const float* q = (const float*)d_in[0];
  const float* k = (const float*)d_in[1];
  const float* v = (const float*)d_in[2];
  const int* mask = (const int*)d_in[3];
  const float* Wq = (const float*)d_in[4];
  const float* bq = (const float*)d_in[5];
  const float* Wk = (const float*)d_in[6];
  const float* bk = (const float*)d_in[7];
  const float* Wv = (const float*)d_in[8];
  const float* bv = (const float*)d_in[9];
  const float* Wp = (const float*)d_in[10];
  const float* bp = (const float*)d_in[11];

  char* ws = (char*)d_ws;
  size_t off = 0;
  auto alloc = [&](size_t bytes) {
    void* p = ws + off;
    off += (bytes + 255) & ~(size_t)255;
    return p;
  };
  u16* in_b = (u16*)alloc((size_t)M * E * 2);  // q/k/v casts, then X
  u16* W_b = (u16*)alloc((size_t)E * E * 2);
  u16* Qh = (u16*)alloc((size_t)M * E * 2);
  u16* Kh = (u16*)alloc((size_t)M * E * 2);
  u16* Vh = (u16*)alloc((size_t)M * E * 2);
  u16* Vt = (u16*)alloc((size_t)M * E * 2);

  dim3 blk(256);
  int gBig = (M * E / 4) / 256;  // 8192
  int gW = (E * E / 4) / 256;    // 1024

  cast_bf16<<<gBig, blk, 0, stream>>>(q, in_b, M * E);
  cast_bf16<<<gW, blk, 0, stream>>>(Wq, W_b, E * E);
  gemm_bt<1><<<512, blk, 0, stream>>>(in_b, W_b, bq, Qh, E);

  cast_bf16<<<gBig, blk, 0, stream>>>(k, in_b, M * E);
  cast_bf16<<<gW, blk, 0, stream>>>(Wk, W_b, E * E);
  gemm_bt<1><<<512, blk, 0, stream>>>(in_b, W_b, bk, Kh, E);

  cast_bf16<<<gBig, blk, 0, stream>>>(v, in_b, M * E);
  cast_bf16<<<gW, blk, 0, stream>>>(Wv, W_b, E * E);
  gemm_bt<0><<<512, blk, 0, stream>>>(in_b, W_b, bv, Vh, E);

  transpose_v<<<2048, blk, 0, stream>>>(Vh, Vt);
  attn_fwd<<<2048, blk, 0, stream>>>(Qh, Kh, Vt, mask, in_b);

  cast_bf16<<<gW, blk, 0, stream>>>(Wp, W_b, E * E);
  gemm_bt<2><<<512, blk, 0, stream>>>(in_b, W_b, bp, d_out, E);
}

// Round 2
// 281.964 us; speedup vs baseline: 1.1803x; 1.1803x over previous
//
#include <hip/hip_runtime.h>

typedef unsigned short u16;
typedef unsigned int u32;
typedef short bf16x8 __attribute__((ext_vector_type(8)));
typedef float f32x4 __attribute__((ext_vector_type(4)));
typedef float f32x16 __attribute__((ext_vector_type(16)));

constexpr int Bb = 8, S = 1024, E = 1024, H = 16, D = 64;
constexpr int M = Bb * S;  // 8192

__device__ inline u16 f2bf(float f) {
  unsigned u = __builtin_bit_cast(unsigned, f);
  return (u16)((u + 0x7fffu + ((u >> 16) & 1u)) >> 16);
}

__device__ inline f32x4 mfma16(bf16x8 a, bf16x8 b, f32x4 c) {
  return __builtin_amdgcn_mfma_f32_16x16x32_bf16(a, b, c, 0, 0, 0);
}
__device__ inline f32x16 mfma32(bf16x8 a, bf16x8 b, f32x16 c) {
  return __builtin_amdgcn_mfma_f32_32x32x16_bf16(a, b, c, 0, 0, 0);
}

__device__ inline u32 cvtpk_bf16(float lo, float hi) {
  u32 r;
  asm volatile("v_cvt_pk_bf16_f32 %0, %1, %2" : "=v"(r) : "v"(lo), "v"(hi));
  return r;
}

__device__ inline void gld16(const u16* g, u16* l) {
  __builtin_amdgcn_global_load_lds(
      (const __attribute__((address_space(1))) void*)g,
      (__attribute__((address_space(3))) void*)l, 16, 0, 0);
}

// ---------------- cast fp32 -> bf16 ----------------
__global__ __launch_bounds__(256) void cast_bf16(const float* __restrict__ in,
                                                 u16* __restrict__ out, int n) {
  int i = (blockIdx.x * blockDim.x + threadIdx.x) * 4;
  if (i >= n) return;
  float4 v = *(const float4*)(in + i);
  u16 o[4] = {f2bf(v.x), f2bf(v.y), f2bf(v.z), f2bf(v.w)};
  *(uint2*)(out + i) = *(const uint2*)o;
}

// ---------------- GEMM: C = A(MxK) * Bm(NxK)^T + bias ----------------
// EPI: 0 = bf16 out, 1 = bf16 out + RoPE, 2 = f32 out
template <int EPI>
__global__ __launch_bounds__(256) void gemm_bt(const u16* __restrict__ A,
                                               const u16* __restrict__ Bm,
                                               const float* __restrict__ bias,
                                               void* __restrict__ Cout, int K) {
  constexpr int N = 1024;
  __shared__ u16 As[4 * 128 * 8];  // [kb][row][8]
  __shared__ u16 Bs[4 * 128 * 8];
  int bid = blockIdx.x;
  int mb = bid >> 3, nb = bid & 7;
  int m0 = mb * 128, n0 = nb * 128;
  int tid = threadIdx.x, lane = tid & 63, wid = tid >> 6;
  int wr = wid >> 1, wc = wid & 1;
  int fr = lane & 15, fq = lane >> 4;

  f32x4 acc[4][4] = {};
  const bf16x8* As8 = (const bf16x8*)As;
  const bf16x8* Bs8 = (const bf16x8*)Bs;

  for (int k0 = 0; k0 < K; k0 += 32) {
#pragma unroll
    for (int c2 = 0; c2 < 2; ++c2) {
      int chunk = wid * 2 + c2;
      int kb = chunk >> 1, rh = (chunk & 1) * 64;
      gld16(A + (size_t)(m0 + rh + lane) * K + k0 + kb * 8, &As[chunk * 512 + lane * 8]);
      gld16(Bm + (size_t)(n0 + rh + lane) * K + k0 + kb * 8, &Bs[chunk * 512 + lane * 8]);
    }
    __syncthreads();
    bf16x8 af[4], bfr[4];
#pragma unroll
    for (int m = 0; m < 4; ++m) af[m] = As8[fq * 128 + wr * 64 + m * 16 + fr];
#pragma unroll
    for (int n = 0; n < 4; ++n) bfr[n] = Bs8[fq * 128 + wc * 64 + n * 16 + fr];
#pragma unroll
    for (int m = 0; m < 4; ++m)
#pragma unroll
      for (int n = 0; n < 4; ++n) acc[m][n] = mfma16(af[m], bfr[n], acc[m][n]);
    __syncthreads();
  }

#pragma unroll
  for (int m = 0; m < 4; ++m) {
#pragma unroll
    for (int j = 0; j < 4; ++j) {
      int r = m0 + wr * 64 + m * 16 + fq * 4 + j;
      if (EPI == 1) {
        int s = r & (S - 1);
#pragma unroll
        for (int n = 0; n < 2; ++n) {
          int c = n0 + wc * 64 + n * 16 + fr;
          int d1 = c & 63;  // in [0,32)
          float x1 = acc[m][n][j] + bias[c];
          float x2 = acc[m][n + 2][j] + bias[c + 32];
          float invf = exp2f((float)d1 * (-13.287712379549449f / 32.f));
          float ang = (float)s * invf;
          float sn, cs;
          sincosf(ang, &sn, &cs);
          ((u16*)Cout)[(size_t)r * N + c] = f2bf(x1 * cs - x2 * sn);
          ((u16*)Cout)[(size_t)r * N + c + 32] = f2bf(x1 * sn + x2 * cs);
        }
      } else if (EPI == 0) {
#pragma unroll
        for (int n = 0; n < 4; ++n) {
          int c = n0 + wc * 64 + n * 16 + fr;
          ((u16*)Cout)[(size_t)r * N + c] = f2bf(acc[m][n][j] + bias[c]);
        }
      } else {
#pragma unroll
        for (int n = 0; n < 4; ++n) {
          int c = n0 + wc * 64 + n * 16 + fr;
          ((float*)Cout)[(size_t)r * N + c] = acc[m][n][j] + bias[c];
        }
      }
    }
  }
}

// ---------------- V transpose: (B,S,E) -> (B,H,D,S) ----------------
__global__ __launch_bounds__(256) void transpose_v(const u16* __restrict__ Vh,
                                                   u16* __restrict__ Vt) {
  __shared__ u16 t[64][80];
  int bid = blockIdx.x;  // B*H*16
  int s0 = (bid & 15) * 64;
  int bh = bid >> 4;
  int b = bh >> 4, h = bh & 15;
  int tid = threadIdx.x;
  {
    int sl = tid >> 2, d4 = (tid & 3) * 16;
    const uint4* src = (const uint4*)(Vh + (size_t)(b * S + s0 + sl) * E + h * 64 + d4);
    uint4 v0 = src[0], v1 = src[1];
    *(uint4*)&t[sl][d4] = v0;
    *(uint4*)&t[sl][d4 + 8] = v1;
  }
  __syncthreads();
  {
    int dl = tid >> 2, s4 = (tid & 3) * 16;
    u16 tmp[16];
#pragma unroll
    for (int e = 0; e < 16; ++e) tmp[e] = t[s4 + e][dl];
    u16* dst = Vt + (size_t)((b * H + h) * D + dl) * S + s0 + s4;
    *(uint4*)dst = *(const uint4*)tmp;
    *(uint4*)(dst + 8) = *(const uint4*)(tmp + 8);
  }
}

// ---------------- flash attention (swapped-QK^T, 32x32 MFMA) ----------------
// 4 waves/block, 32 q-rows/wave => 128 q-rows/block. KVBLK=64, double-buffered.
// Lane owns q = q0 + wid*32 + (lane&31); col of all MFMA outputs = that q.
__global__ __launch_bounds__(256) void attn_fwd(const u16* __restrict__ Qh,
                                                const u16* __restrict__ Kh,
                                                const u16* __restrict__ Vt,
                                                const int* __restrict__ mask,
                                                u16* __restrict__ X) {
  __shared__ u16 Ks[2][8 * 64 * 8];  // [buf][d-chunk][key-slot][8]
  __shared__ u16 Vs[2][8 * 64 * 8];  // [buf][k-chunk][d-slot][8]
  __shared__ float maskb[S];
  int bid = blockIdx.x;
  int qt = bid & 7;  // 8 q-tiles of 128
  int bh = bid >> 3;
  int b = bh >> 4, h = bh & 15;
  int q0 = qt * 128;
  int tid = threadIdx.x, lane = tid & 63, wid = tid >> 6;
  int hi = lane >> 5, r5 = lane & 31;
  int sw_r5 = r5 ^ ((r5 >> 3) & 3);  // bank-swizzle involution (XOR bits 3,4 into 0,1)

  const int* mrow = mask + b * S;
  for (int i = tid; i < S; i += 256) maskb[i] = mrow[i] ? 0.f : -1e20f;

  // Q fragments: lane holds Q[q0+wid*32+r5][dc*16 + hi*8 .. +8]
  bf16x8 aq[4];
  {
    const u16* qp = Qh + (size_t)(b * S + q0 + wid * 32 + r5) * E + h * 64 + hi * 8;
#pragma unroll
    for (int dc = 0; dc < 4; ++dc) aq[dc] = *(const bf16x8*)(qp + dc * 16);
  }
  f32x16 oacc0 = {}, oacc1 = {};
  float mrun = -INFINITY, lrun = 0.f;

  size_t kbase = (size_t)(b * S) * E + h * 64;
  size_t vbase = (size_t)((b * H + h) * D) * S;
  const bf16x8* Ks8 = (const bf16x8*)Ks;
  const bf16x8* Vs8 = (const bf16x8*)Vs;
  int swl = lane ^ ((lane >> 3) & 3);

  auto stage = [&](int buf, int t) {
    int kv0 = t * 64;
#pragma unroll
    for (int c4 = 0; c4 < 4; ++c4) {
      int ch = wid * 4 + c4;
      if (ch < 8) {
        // Ks slot `lane` of chunk ch holds K row (kv0 + swl), dwords ch*8..
        gld16(Kh + kbase + (size_t)(kv0 + swl) * E + ch * 8, &Ks[buf][ch * 512 + lane * 8]);
      } else {
        int c = ch - 8;
        // Vs slot `lane` of chunk c holds V^T row d=swl, keys kv0 + c*8..
        gld16(Vt + vbase + (size_t)swl * S + kv0 + c * 8, &Vs[buf][c * 512 + lane * 8]);
      }
    }
  };

  stage(0, 0);
  __syncthreads();
  int cur = 0;
  for (int t = 0; t < 16; ++t) {
    if (t < 15) stage(cur ^ 1, t + 1);
    int kv0 = t * 64;

    // ---- S^T = K Q^T : p{0,1}[r] = S[k = kv0 + kb*32 + (r&3)+8*(r>>2)+4*hi][q] ----
    f32x16 p0 = {}, p1 = {};
#pragma unroll
    for (int dc = 0; dc < 4; ++dc) {
      bf16x8 k0 = Ks8[cur * 512 + (dc * 2 + hi) * 64 + sw_r5];
      bf16x8 k1 = Ks8[cur * 512 + (dc * 2 + hi) * 64 + 32 + sw_r5];
      p0 = mfma32(k0, aq[dc], p0);
      p1 = mfma32(k1, aq[dc], p1);
    }

    // ---- scale + mask bias (broadcast LDS reads) ----
#pragma unroll
    for (int g = 0; g < 4; ++g) {
      f32x4 mb0 = *(const f32x4*)&maskb[kv0 + g * 8 + hi * 4];
      f32x4 mb1 = *(const f32x4*)&maskb[kv0 + 32 + g * 8 + hi * 4];
#pragma unroll
      for (int jj = 0; jj < 4; ++jj) {
        p0[g * 4 + jj] = fmaf(p0[g * 4 + jj], 0.125f, mb0[jj]);
        p1[g * 4 + jj] = fmaf(p1[g * 4 + jj], 0.125f, mb1[jj]);
      }
    }

    // ---- online softmax, one q-row per lane (partner = lane^32) ----
    float mt = p0[0];
#pragma unroll
    for (int i = 1; i < 16; ++i) mt = fmaxf(mt, p0[i]);
#pragma unroll
    for (int i = 0; i < 16; ++i) mt = fmaxf(mt, p1[i]);
    mt = fmaxf(mt, __shfl_xor(mt, 32));
    float mnew = fmaxf(mrun, mt);
    float fac = __expf(mrun - mnew);
    float rs = 0.f;
#pragma unroll
    for (int i = 0; i < 16; ++i) {
      p0[i] = __expf(p0[i] - mnew);
      rs += p0[i];
    }
#pragma unroll
    for (int i = 0; i < 16; ++i) {
      p1[i] = __expf(p1[i] - mnew);
      rs += p1[i];
    }
    rs += __shfl_xor(rs, 32);
    lrun = lrun * fac + rs;
    mrun = mnew;
#pragma unroll
    for (int i = 0; i < 16; ++i) {
      oacc0[i] *= fac;
      oacc1[i] *= fac;
    }

    // ---- P relayout (cvt_pk + permlane32_swap) and PV: O^T = V^T P^T ----
#pragma unroll
    for (int kc = 0; kc < 4; ++kc) {
      int gA = (kc & 1) * 2, gB = gA + 1;
      u32 a0, a1, b0, b1;
      if (kc < 2) {
        a0 = cvtpk_bf16(p0[gA * 4 + 0], p0[gA * 4 + 1]);
        a1 = cvtpk_bf16(p0[gA * 4 + 2], p0[gA * 4 + 3]);
        b0 = cvtpk_bf16(p0[gB * 4 + 0], p0[gB * 4 + 1]);
        b1 = cvtpk_bf16(p0[gB * 4 + 2], p0[gB * 4 + 3]);
      } else {
        a0 = cvtpk_bf16(p1[gA * 4 + 0], p1[gA * 4 + 1]);
        a1 = cvtpk_bf16(p1[gA * 4 + 2], p1[gA * 4 + 3]);
        b0 = cvtpk_bf16(p1[gB * 4 + 0], p1[gB * 4 + 1]);
        b1 = cvtpk_bf16(p1[gB * 4 + 2], p1[gB * 4 + 3]);
      }
      asm volatile("v_permlane32_swap_b32 %0, %1" : "+v"(a0), "+v"(b0));
      asm volatile("v_permlane32_swap_b32 %0, %1" : "+v"(a1), "+v"(b1));
      union {
        u32 w[4];
        bf16x8 v;
      } pu;
      pu.w[0] = a0;  // j=0,1
      pu.w[1] = a1;  // j=2,3
      pu.w[2] = b0;  // j=4,5
      pu.w[3] = b1;  // j=6,7
      bf16x8 av0 = Vs8[cur * 512 + (kc * 2 + hi) * 64 + sw_r5];
      bf16x8 av1 = Vs8[cur * 512 + (kc * 2 + hi) * 64 + 32 + sw_r5];
      oacc0 = mfma32(av0, pu.v, oacc0);
      oacc1 = mfma32(av1, pu.v, oacc1);
    }
    __syncthreads();
    cur ^= 1;
  }

  // ---- epilogue: O[q][d] = oacc[dn][r]/l at d = dn*32 + 8g + 4hi + (r&3) ----
  float rl = 1.f / lrun;
  u16* xrow = X + (size_t)(b * S + q0 + wid * 32 + r5) * E + h * 64;
#pragma unroll
  for (int dn = 0; dn < 2; ++dn) {
#pragma unroll
    for (int g = 0; g < 4; ++g) {
#pragma unroll
      for (int m2 = 0; m2 < 2; ++m2) {
        float v0, v1;
        if (dn == 0) {
          v0 = oacc0[g * 4 + m2 * 2] * rl;
          v1 = oacc0[g * 4 + m2 * 2 + 1] * rl;
        } else {
          v0 = oacc1[g * 4 + m2 * 2] * rl;
          v1 = oacc1[g * 4 + m2 * 2 + 1] * rl;
        }
        u16 pr[2] = {f2bf(v0), f2bf(v1)};
        *(u32*)(xrow + dn * 32 + g * 8 + hi * 4 + m2 * 2) = *(const u32*)pr;
      }
    }
  }
}

extern "C" void kernel_launch(void* const* d_in, const int* in_sizes, int n_in,
                              void* d_out, int out_size, void* d_ws, size_t ws_size,
                              hipStream_t stream) {
  const float* q = (const float*)d_in[0];
  const float* k = (const float*)d_in[1];
  const float* v = (const float*)d_in[2];
  const int* mask = (const int*)d_in[3];
  const float* Wq = (const float*)d_in[4];
  const float* bq = (const float*)d_in[5];
  const float* Wk = (const float*)d_in[6];
  const float* bk = (const float*)d_in[7];
  const float* Wv = (const float*)d_in[8];
  const float* bv = (const float*)d_in[9];
  const float* Wp = (const float*)d_in[10];
  const float* bp = (const float*)d_in[11];

  char* ws = (char*)d_ws;
  size_t off = 0;
  auto alloc = [&](size_t bytes) {
    void* p = ws + off;
    off += (bytes + 255) & ~(size_t)255;
    return p;
  };
  u16* in_b = (u16*)alloc((size_t)M * E * 2);  // q/k/v casts, then X
  u16* W_b = (u16*)alloc((size_t)E * E * 2);
  u16* Qh = (u16*)alloc((size_t)M * E * 2);
  u16* Kh = (u16*)alloc((size_t)M * E * 2);
  u16* Vh = (u16*)alloc((size_t)M * E * 2);
  u16* Vt = (u16*)alloc((size_t)M * E * 2);

  dim3 blk(256);
  int gBig = (M * E / 4) / 256;  // 8192
  int gW = (E * E / 4) / 256;    // 1024

  cast_bf16<<<gBig, blk, 0, stream>>>(q, in_b, M * E);
  cast_bf16<<<gW, blk, 0, stream>>>(Wq, W_b, E * E);
  gemm_bt<1><<<512, blk, 0, stream>>>(in_b, W_b, bq, Qh, E);

  cast_bf16<<<gBig, blk, 0, stream>>>(k, in_b, M * E);
  cast_bf16<<<gW, blk, 0, stream>>>(Wk, W_b, E * E);
  gemm_bt<1><<<512, blk, 0, stream>>>(in_b, W_b, bk, Kh, E);

  cast_bf16<<<gBig, blk, 0, stream>>>(v, in_b, M * E);
  cast_bf16<<<gW, blk, 0, stream>>>(Wv, W_b, E * E);
  gemm_bt<0><<<512, blk, 0, stream>>>(in_b, W_b, bv, Vh, E);

  transpose_v<<<2048, blk, 0, stream>>>(Vh, Vt);
  attn_fwd<<<1024, blk, 0, stream>>>(Qh, Kh, Vt, mask, in_b);

  cast_bf16<<<gW, blk, 0, stream>>>(Wp, W_b, E * E);
  gemm_bt<2><<<512, blk, 0, stream>>>(in_b, W_b, bp, d_out, E);
}

// Round 3
// 278.733 us; speedup vs baseline: 1.1940x; 1.0116x over previous
//
#include <hip/hip_runtime.h>

typedef unsigned short u16;
typedef unsigned int u32;
typedef short bf16x8 __attribute__((ext_vector_type(8)));
typedef float f32x4 __attribute__((ext_vector_type(4)));
typedef float f32x16 __attribute__((ext_vector_type(16)));

constexpr int Bb = 8, S = 1024, E = 1024, H = 16, D = 64;
constexpr int M = Bb * S;  // 8192

__device__ inline u16 f2bf(float f) {
  unsigned u = __builtin_bit_cast(unsigned, f);
  return (u16)((u + 0x7fffu + ((u >> 16) & 1u)) >> 16);
}

__device__ inline f32x4 mfma16(bf16x8 a, bf16x8 b, f32x4 c) {
  return __builtin_amdgcn_mfma_f32_16x16x32_bf16(a, b, c, 0, 0, 0);
}
__device__ inline f32x16 mfma32(bf16x8 a, bf16x8 b, f32x16 c) {
  return __builtin_amdgcn_mfma_f32_32x32x16_bf16(a, b, c, 0, 0, 0);
}

__device__ inline u32 cvtpk_bf16(float lo, float hi) {
  u32 r;
  asm volatile("v_cvt_pk_bf16_f32 %0, %1, %2" : "=v"(r) : "v"(lo), "v"(hi));
  return r;
}

__device__ inline float exp2a(float x) {
  float r;
  asm("v_exp_f32 %0, %1" : "=v"(r) : "v"(x));
  return r;
}

__device__ inline void gld16(const u16* g, u16* l) {
  __builtin_amdgcn_global_load_lds(
      (const __attribute__((address_space(1))) void*)g,
      (__attribute__((address_space(3))) void*)l, 16, 0, 0);
}

// ---------------- cast fp32 -> bf16 ----------------
__global__ __launch_bounds__(256) void cast_bf16(const float* __restrict__ in,
                                                 u16* __restrict__ out, int n) {
  int i = (blockIdx.x * blockDim.x + threadIdx.x) * 4;
  if (i >= n) return;
  float4 v = *(const float4*)(in + i);
  u16 o[4] = {f2bf(v.x), f2bf(v.y), f2bf(v.z), f2bf(v.w)};
  *(uint2*)(out + i) = *(const uint2*)o;
}

// ---------------- GEMM: C = A(MxK) * Bm(NxK)^T + bias ----------------
// Pipelined half-K-tile schedule: BM=256, BN=128, BK_half=32, 4 LDS buffers,
// counted vmcnt (steady 6), raw barriers, setprio around MFMA cluster.
// 512 threads = 8 waves (4 Mx2 N), per-wave 64x64, 16 mfma16 per half-tile.
// EPI: 0 = bf16 out, 1 = bf16 out + RoPE, 2 = f32 out
template <int EPI>
__global__ __launch_bounds__(512, 2) void gemm_bt(const u16* __restrict__ A,
                                                  const u16* __restrict__ Bm,
                                                  const float* __restrict__ bias,
                                                  void* __restrict__ Cout) {
  constexpr int K = 1024;
  constexpr int N = 1024;
  __shared__ u16 smem[49152];  // 96 KB = 4 bufs x (A 16KB + B 8KB)
  char* sm = (char*)smem;

  int wg = blockIdx.x;
  int swz = (wg & 7) * 32 + (wg >> 3);  // XCD-chunked (256 % 8 == 0, bijective)
  int mb = swz >> 3, nb = swz & 7;
  int m0 = mb * 256, n0 = nb * 128;
  int tid = threadIdx.x, lane = tid & 63, wid = tid >> 6;
  int wr = wid >> 1, wn = wid & 1;
  int fr = lane & 15, fq = lane >> 4;

  // staging: per half-tile each thread issues 2 A-loads + 1 B-load (16 B each).
  // LDS layout per buffer: A [kseg][srow][16B], srow = (row + 2*kseg) & 255;
  //                        B at +16384, srowB = (row + 2*kseg) & 127.
  const u16* srcA0;
  const u16* srcA1;
  const u16* srcB;
  int dstA0, dstA1, dstB;
  {
    int g0 = wid * 128 + lane;
    int ks0 = g0 >> 8, sr0 = g0 & 255;
    srcA0 = A + (size_t)(m0 + ((sr0 + 256 - 2 * ks0) & 255)) * K + ks0 * 8;
    dstA0 = (wid * 128) * 16;
    int g1 = wid * 128 + 64 + lane;
    int ks1 = g1 >> 8, sr1 = g1 & 255;
    srcA1 = A + (size_t)(m0 + ((sr1 + 256 - 2 * ks1) & 255)) * K + ks1 * 8;
    dstA1 = (wid * 128 + 64) * 16;
    int gB = wid * 64 + lane;
    int ksB = gB >> 7, srB = gB & 127;
    srcB = Bm + (size_t)(n0 + ((srB + 128 - 2 * ksB) & 127)) * K + ksB * 8;
    dstB = 16384 + (wid * 64) * 16;
  }
  // fragment read byte-offsets (swizzled to match staging rotation)
  int offA[4], offB[4];
#pragma unroll
  for (int m = 0; m < 4; ++m)
    offA[m] = fq * 4096 + (((wr * 64 + m * 16 + fr + 2 * fq) & 255) * 16);
#pragma unroll
  for (int n = 0; n < 4; ++n)
    offB[n] = 16384 + fq * 2048 + (((wn * 64 + n * 16 + fr + 2 * fq) & 127) * 16);

  f32x4 acc[4][4] = {};
  bf16x8 a0[4], b0[4], a1[4], b1[4];

#define STAGE(H)                                         \
  do {                                                   \
    int bb_ = ((H) & 3) * 24576;                         \
    gld16(srcA0 + (H) * 32, (u16*)(sm + bb_ + dstA0));   \
    gld16(srcA1 + (H) * 32, (u16*)(sm + bb_ + dstA1));   \
    gld16(srcB + (H) * 32, (u16*)(sm + bb_ + dstB));     \
  } while (0)
#define READF(H, AR, BR)                                             \
  do {                                                               \
    int bb_ = ((H) & 3) * 24576;                                     \
    _Pragma("unroll") for (int m_ = 0; m_ < 4; ++m_)                 \
        AR[m_] = *(const bf16x8*)(sm + bb_ + offA[m_]);              \
    _Pragma("unroll") for (int n_ = 0; n_ < 4; ++n_)                 \
        BR[n_] = *(const bf16x8*)(sm + bb_ + offB[n_]);              \
  } while (0)
#define MFMAC(AR, BR)                                                \
  do {                                                               \
    __builtin_amdgcn_s_setprio(1);                                   \
    _Pragma("unroll") for (int m_ = 0; m_ < 4; ++m_)                 \
        _Pragma("unroll") for (int n_ = 0; n_ < 4; ++n_)             \
            acc[m_][n_] = mfma16(AR[m_], BR[n_], acc[m_][n_]);       \
    __builtin_amdgcn_s_setprio(0);                                   \
  } while (0)
#define WAITVM(N) asm volatile("s_waitcnt vmcnt(" #N ")" ::: "memory")

  STAGE(0);
  STAGE(1);
  STAGE(2);
  WAITVM(6);
  __builtin_amdgcn_s_barrier();
  READF(0, a0, b0);

  for (int h = 0; h < 28; h += 2) {
    // iter h (even): consumes a0/b0 = frags(h), reads frags(h+1) -> a1/b1
    STAGE(h + 3);
    WAITVM(6);
    __builtin_amdgcn_s_barrier();
    READF(h + 1, a1, b1);
    MFMAC(a0, b0);
    // iter h+1 (odd)
    STAGE(h + 4);
    WAITVM(6);
    __builtin_amdgcn_s_barrier();
    READF(h + 2, a0, b0);
    MFMAC(a1, b1);
  }
  // iter 28
  STAGE(31);
  WAITVM(6);
  __builtin_amdgcn_s_barrier();
  READF(29, a1, b1);
  MFMAC(a0, b0);
  // iter 29
  WAITVM(3);
  __builtin_amdgcn_s_barrier();
  READF(30, a0, b0);
  MFMAC(a1, b1);
  // iter 30
  WAITVM(0);
  __builtin_amdgcn_s_barrier();
  READF(31, a1, b1);
  MFMAC(a0, b0);
  // iter 31
  MFMAC(a1, b1);

#undef STAGE
#undef READF
#undef MFMAC
#undef WAITVM

#pragma unroll
  for (int m = 0; m < 4; ++m) {
#pragma unroll
    for (int j = 0; j < 4; ++j) {
      int r = m0 + wr * 64 + m * 16 + fq * 4 + j;
      if (EPI == 1) {
        int s = r & (S - 1);
#pragma unroll
        for (int n = 0; n < 2; ++n) {
          int c = n0 + wn * 64 + n * 16 + fr;
          int d1 = c & 63;  // in [0,32)
          float x1 = acc[m][n][j] + bias[c];
          float x2 = acc[m][n + 2][j] + bias[c + 32];
          float invf = exp2f((float)d1 * (-13.287712379549449f / 32.f));
          float ang = (float)s * invf;
          float sn, cs;
          sincosf(ang, &sn, &cs);
          ((u16*)Cout)[(size_t)r * N + c] = f2bf(x1 * cs - x2 * sn);
          ((u16*)Cout)[(size_t)r * N + c + 32] = f2bf(x1 * sn + x2 * cs);
        }
      } else if (EPI == 0) {
#pragma unroll
        for (int n = 0; n < 4; ++n) {
          int c = n0 + wn * 64 + n * 16 + fr;
          ((u16*)Cout)[(size_t)r * N + c] = f2bf(acc[m][n][j] + bias[c]);
        }
      } else {
#pragma unroll
        for (int n = 0; n < 4; ++n) {
          int c = n0 + wn * 64 + n * 16 + fr;
          ((float*)Cout)[(size_t)r * N + c] = acc[m][n][j] + bias[c];
        }
      }
    }
  }
}

// ---------------- V transpose: (B,S,E) -> (B,H,D,S) ----------------
__global__ __launch_bounds__(256) void transpose_v(const u16* __restrict__ Vh,
                                                   u16* __restrict__ Vt) {
  __shared__ u16 t[64][80];
  int bid = blockIdx.x;  // B*H*16
  int s0 = (bid & 15) * 64;
  int bh = bid >> 4;
  int b = bh >> 4, h = bh & 15;
  int tid = threadIdx.x;
  {
    int sl = tid >> 2, d4 = (tid & 3) * 16;
    const uint4* src = (const uint4*)(Vh + (size_t)(b * S + s0 + sl) * E + h * 64 + d4);
    uint4 v0 = src[0], v1 = src[1];
    *(uint4*)&t[sl][d4] = v0;
    *(uint4*)&t[sl][d4 + 8] = v1;
  }
  __syncthreads();
  {
    int dl = tid >> 2, s4 = (tid & 3) * 16;
    u16 tmp[16];
#pragma unroll
    for (int e = 0; e < 16; ++e) tmp[e] = t[s4 + e][dl];
    u16* dst = Vt + (size_t)((b * H + h) * D + dl) * S + s0 + s4;
    *(uint4*)dst = *(const uint4*)tmp;
    *(uint4*)(dst + 8) = *(const uint4*)(tmp + 8);
  }
}

// ---------------- flash attention (swapped-QK^T, 32x32 MFMA) ----------------
// exp2-domain softmax + defer-max (T13).
__global__ __launch_bounds__(256) void attn_fwd(const u16* __restrict__ Qh,
                                                const u16* __restrict__ Kh,
                                                const u16* __restrict__ Vt,
                                                const int* __restrict__ mask,
                                                u16* __restrict__ X) {
  __shared__ u16 Ks[2][8 * 64 * 8];  // [buf][d-chunk][key-slot][8]
  __shared__ u16 Vs[2][8 * 64 * 8];  // [buf][k-chunk][d-slot][8]
  __shared__ float maskb[S];
  constexpr float SC = 0.18033688011112042f;  // 0.125 * log2(e)
  int bid = blockIdx.x;
  int qt = bid & 7;  // 8 q-tiles of 128
  int bh = bid >> 3;
  int b = bh >> 4, h = bh & 15;
  int q0 = qt * 128;
  int tid = threadIdx.x, lane = tid & 63, wid = tid >> 6;
  int hi = lane >> 5, r5 = lane & 31;
  int sw_r5 = r5 ^ ((r5 >> 3) & 3);  // bank-swizzle involution

  const int* mrow = mask + b * S;
  for (int i = tid; i < S; i += 256) maskb[i] = mrow[i] ? 0.f : -1e30f;

  bf16x8 aq[4];
  {
    const u16* qp = Qh + (size_t)(b * S + q0 + wid * 32 + r5) * E + h * 64 + hi * 8;
#pragma unroll
    for (int dc = 0; dc < 4; ++dc) aq[dc] = *(const bf16x8*)(qp + dc * 16);
  }
  f32x16 oacc0 = {}, oacc1 = {};
  float mrun = -INFINITY, lrun = 0.f;

  size_t kbase = (size_t)(b * S) * E + h * 64;
  size_t vbase = (size_t)((b * H + h) * D) * S;
  const bf16x8* Ks8 = (const bf16x8*)Ks;
  const bf16x8* Vs8 = (const bf16x8*)Vs;
  int swl = lane ^ ((lane >> 3) & 3);

  auto stage = [&](int buf, int t) {
    int kv0 = t * 64;
#pragma unroll
    for (int c4 = 0; c4 < 4; ++c4) {
      int ch = wid * 4 + c4;
      if (ch < 8) {
        gld16(Kh + kbase + (size_t)(kv0 + swl) * E + ch * 8, &Ks[buf][ch * 512 + lane * 8]);
      } else {
        int c = ch - 8;
        gld16(Vt + vbase + (size_t)swl * S + kv0 + c * 8, &Vs[buf][c * 512 + lane * 8]);
      }
    }
  };

  stage(0, 0);
  __syncthreads();
  int cur = 0;
  for (int t = 0; t < 16; ++t) {
    if (t < 15) stage(cur ^ 1, t + 1);
    int kv0 = t * 64;

    // ---- S^T = K Q^T ----
    f32x16 p0 = {}, p1 = {};
#pragma unroll
    for (int dc = 0; dc < 4; ++dc) {
      bf16x8 k0 = Ks8[cur * 512 + (dc * 2 + hi) * 64 + sw_r5];
      bf16x8 k1 = Ks8[cur * 512 + (dc * 2 + hi) * 64 + 32 + sw_r5];
      p0 = mfma32(k0, aq[dc], p0);
      p1 = mfma32(k1, aq[dc], p1);
    }

    // ---- scale to log2-domain + mask bias ----
#pragma unroll
    for (int g = 0; g < 4; ++g) {
      f32x4 mb0 = *(const f32x4*)&maskb[kv0 + g * 8 + hi * 4];
      f32x4 mb1 = *(const f32x4*)&maskb[kv0 + 32 + g * 8 + hi * 4];
#pragma unroll
      for (int jj = 0; jj < 4; ++jj) {
        p0[g * 4 + jj] = fmaf(p0[g * 4 + jj], SC, mb0[jj]);
        p1[g * 4 + jj] = fmaf(p1[g * 4 + jj], SC, mb1[jj]);
      }
    }

    // ---- online softmax (base-2), defer-max ----
    float mt = p0[0];
#pragma unroll
    for (int i = 1; i < 16; ++i) mt = fmaxf(mt, p0[i]);
#pragma unroll
    for (int i = 0; i < 16; ++i) mt = fmaxf(mt, p1[i]);
    mt = fmaxf(mt, __shfl_xor(mt, 32));
    if (!__all(mt - mrun <= 8.f)) {
      float mnew = fmaxf(mrun, mt);
      float fac = exp2a(mrun - mnew);
      lrun *= fac;
#pragma unroll
      for (int i = 0; i < 16; ++i) {
        oacc0[i] *= fac;
        oacc1[i] *= fac;
      }
      mrun = mnew;
    }
    float rs = 0.f;
#pragma unroll
    for (int i = 0; i < 16; ++i) {
      p0[i] = exp2a(p0[i] - mrun);
      rs += p0[i];
    }
#pragma unroll
    for (int i = 0; i < 16; ++i) {
      p1[i] = exp2a(p1[i] - mrun);
      rs += p1[i];
    }
    rs += __shfl_xor(rs, 32);
    lrun += rs;

    // ---- P relayout (cvt_pk + permlane32_swap) and PV: O^T = V^T P^T ----
#pragma unroll
    for (int kc = 0; kc < 4; ++kc) {
      int gA = (kc & 1) * 2, gB = gA + 1;
      u32 a0, a1, b0, b1;
      if (kc < 2) {
        a0 = cvtpk_bf16(p0[gA * 4 + 0], p0[gA * 4 + 1]);
        a1 = cvtpk_bf16(p0[gA * 4 + 2], p0[gA * 4 + 3]);
        b0 = cvtpk_bf16(p0[gB * 4 + 0], p0[gB * 4 + 1]);
        b1 = cvtpk_bf16(p0[gB * 4 + 2], p0[gB * 4 + 3]);
      } else {
        a0 = cvtpk_bf16(p1[gA * 4 + 0], p1[gA * 4 + 1]);
        a1 = cvtpk_bf16(p1[gA * 4 + 2], p1[gA * 4 + 3]);
        b0 = cvtpk_bf16(p1[gB * 4 + 0], p1[gB * 4 + 1]);
        b1 = cvtpk_bf16(p1[gB * 4 + 2], p1[gB * 4 + 3]);
      }
      asm volatile("v_permlane32_swap_b32 %0, %1" : "+v"(a0), "+v"(b0));
      asm volatile("v_permlane32_swap_b32 %0, %1" : "+v"(a1), "+v"(b1));
      union {
        u32 w[4];
        bf16x8 v;
      } pu;
      pu.w[0] = a0;
      pu.w[1] = a1;
      pu.w[2] = b0;
      pu.w[3] = b1;
      bf16x8 av0 = Vs8[cur * 512 + (kc * 2 + hi) * 64 + sw_r5];
      bf16x8 av1 = Vs8[cur * 512 + (kc * 2 + hi) * 64 + 32 + sw_r5];
      oacc0 = mfma32(av0, pu.v, oacc0);
      oacc1 = mfma32(av1, pu.v, oacc1);
    }
    __syncthreads();
    cur ^= 1;
  }

  float rl = 1.f / lrun;
  u16* xrow = X + (size_t)(b * S + q0 + wid * 32 + r5) * E + h * 64;
#pragma unroll
  for (int dn = 0; dn < 2; ++dn) {
#pragma unroll
    for (int g = 0; g < 4; ++g) {
#pragma unroll
      for (int m2 = 0; m2 < 2; ++m2) {
        float v0, v1;
        if (dn == 0) {
          v0 = oacc0[g * 4 + m2 * 2] * rl;
          v1 = oacc0[g * 4 + m2 * 2 + 1] * rl;
        } else {
          v0 = oacc1[g * 4 + m2 * 2] * rl;
          v1 = oacc1[g * 4 + m2 * 2 + 1] * rl;
        }
        u16 pr[2] = {f2bf(v0), f2bf(v1)};
        *(u32*)(xrow + dn * 32 + g * 8 + hi * 4 + m2 * 2) = *(const u32*)pr;
      }
    }
  }
}

extern "C" void kernel_launch(void* const* d_in, const int* in_sizes, int n_in,
                              void* d_out, int out_size, void* d_ws, size_t ws_size,
                              hipStream_t stream) {
  const float* q = (const float*)d_in[0];
  const float* k = (const float*)d_in[1];
  const float* v = (const float*)d_in[2];
  const int* mask = (const int*)d_in[3];
  const float* Wq = (const float*)d_in[4];
  const float* bq = (const float*)d_in[5];
  const float* Wk = (const float*)d_in[6];
  const float* bk = (const float*)d_in[7];
  const float* Wv = (const float*)d_in[8];
  const float* bv = (const float*)d_in[9];
  const float* Wp = (const float*)d_in[10];
  const float* bp = (const float*)d_in[11];

  char* ws = (char*)d_ws;
  size_t off = 0;
  auto alloc = [&](size_t bytes) {
    void* p = ws + off;
    off += (bytes + 255) & ~(size_t)255;
    return p;
  };
  u16* in_b = (u16*)alloc((size_t)M * E * 2);  // q/k/v casts, then X
  u16* W_b = (u16*)alloc((size_t)E * E * 2);
  u16* Qh = (u16*)alloc((size_t)M * E * 2);
  u16* Kh = (u16*)alloc((size_t)M * E * 2);
  u16* Vh = (u16*)alloc((size_t)M * E * 2);
  u16* Vt = (u16*)alloc((size_t)M * E * 2);

  dim3 blk(256);
  int gBig = (M * E / 4) / 256;  // 8192
  int gW = (E * E / 4) / 256;    // 1024

  cast_bf16<<<gBig, blk, 0, stream>>>(q, in_b, M * E);
  cast_bf16<<<gW, blk, 0, stream>>>(Wq, W_b, E * E);
  gemm_bt<1><<<256, 512, 0, stream>>>(in_b, W_b, bq, Qh);

  cast_bf16<<<gBig, blk, 0, stream>>>(k, in_b, M * E);
  cast_bf16<<<gW, blk, 0, stream>>>(Wk, W_b, E * E);
  gemm_bt<1><<<256, 512, 0, stream>>>(in_b, W_b, bk, Kh);

  cast_bf16<<<gBig, blk, 0, stream>>>(v, in_b, M * E);
  cast_bf16<<<gW, blk, 0, stream>>>(Wv, W_b, E * E);
  gemm_bt<0><<<256, 512, 0, stream>>>(in_b, W_b, bv, Vh);

  transpose_v<<<2048, blk, 0, stream>>>(Vh, Vt);
  attn_fwd<<<1024, blk, 0, stream>>>(Qh, Kh, Vt, mask, in_b);

  cast_bf16<<<gW, blk, 0, stream>>>(Wp, W_b, E * E);
  gemm_bt<2><<<256, 512, 0, stream>>>(in_b, W_b, bp, d_out);
}

// Round 4
// 247.639 us; speedup vs baseline: 1.3439x; 1.1256x over previous
//
#include <hip/hip_runtime.h>

typedef unsigned short u16;
typedef unsigned int u32;
typedef short bf16x8 __attribute__((ext_vector_type(8)));
typedef float f32x4 __attribute__((ext_vector_type(4)));
typedef float f32x16 __attribute__((ext_vector_type(16)));

constexpr int Bb = 8, S = 1024, E = 1024, H = 16, D = 64;
constexpr int M = Bb * S;  // 8192

__device__ inline u16 f2bf(float f) {
  unsigned u = __builtin_bit_cast(unsigned, f);
  return (u16)((u + 0x7fffu + ((u >> 16) & 1u)) >> 16);
}

__device__ inline f32x4 mfma16(bf16x8 a, bf16x8 b, f32x4 c) {
  return __builtin_amdgcn_mfma_f32_16x16x32_bf16(a, b, c, 0, 0, 0);
}
__device__ inline f32x16 mfma32(bf16x8 a, bf16x8 b, f32x16 c) {
  return __builtin_amdgcn_mfma_f32_32x32x16_bf16(a, b, c, 0, 0, 0);
}

__device__ inline u32 cvtpk_bf16(float lo, float hi) {
  u32 r;
  asm volatile("v_cvt_pk_bf16_f32 %0, %1, %2" : "=v"(r) : "v"(lo), "v"(hi));
  return r;
}

__device__ inline float exp2a(float x) {
  float r;
  asm("v_exp_f32 %0, %1" : "=v"(r) : "v"(x));
  return r;
}

__device__ inline void gld16(const u16* g, u16* l) {
  __builtin_amdgcn_global_load_lds(
      (const __attribute__((address_space(1))) void*)g,
      (__attribute__((address_space(3))) void*)l, 16, 0, 0);
}

// ---------------- fused cast: q,k,v,Wq,Wk,Wv,Wp -> bf16 ----------------
__global__ __launch_bounds__(256) void prep_cast(
    const float* __restrict__ q, const float* __restrict__ k,
    const float* __restrict__ v, const float* __restrict__ Wq,
    const float* __restrict__ Wk, const float* __restrict__ Wv,
    const float* __restrict__ Wp, u16* __restrict__ qb, u16* __restrict__ kb,
    u16* __restrict__ vb, u16* __restrict__ w4) {
  const size_t NBIG = (size_t)M * E;  // 2^23
  const size_t NW = (size_t)E * E;    // 2^20
  const size_t TOT4 = (NBIG * 3 + NW * 4) / 4;
  for (size_t t = (size_t)blockIdx.x * 256 + threadIdx.x; t < TOT4;
       t += (size_t)gridDim.x * 256) {
    size_t i = t * 4;
    const float* src;
    u16* dst;
    size_t off;
    if (i < 3 * NBIG) {
      int which = (int)(i >> 23);
      off = i & (NBIG - 1);
      src = which == 0 ? q : which == 1 ? k : v;
      dst = which == 0 ? qb : which == 1 ? kb : vb;
    } else {
      size_t j = i - 3 * NBIG;
      int w = (int)(j >> 20);
      off = j & (NW - 1);
      src = w == 0 ? Wq : w == 1 ? Wk : w == 2 ? Wv : Wp;
      dst = w4 + ((size_t)w << 20);
    }
    float4 x = *(const float4*)(src + off);
    u16 o[4] = {f2bf(x.x), f2bf(x.y), f2bf(x.z), f2bf(x.w)};
    *(uint2*)(dst + off) = *(const uint2*)o;
  }
}

// ---------------- GEMM body: C = A(8192xK) * Bm(NxK)^T + bias ----------------
// 128x128 tile, 256 thr (4 waves), single LDS buffer, 2 syncs/iter (m97-style),
// 3 blocks/CU. epi: 1 = bf16+RoPE, 0 = bf16, 2 = f32.
__device__ __forceinline__ void gemm_body(const u16* __restrict__ A,
                                          const u16* __restrict__ Bm,
                                          const float* __restrict__ bias,
                                          u16* __restrict__ outb,
                                          float* __restrict__ outf, int epi,
                                          int wg) {
  constexpr int K = 1024, N = 1024;
  __shared__ u16 As[4 * 128 * 8];  // [kseg][row][8]
  __shared__ u16 Bs[4 * 128 * 8];
  int nb = wg >> 6, mb = wg & 63;  // bid&7 == mb&7: same-A blocks co-XCD
  int m0 = mb * 128, n0 = nb * 128;
  int tid = threadIdx.x, lane = tid & 63, wid = tid >> 6;
  int wr = wid >> 1, wc = wid & 1;
  int fr = lane & 15, fq = lane >> 4;

  f32x4 acc[4][4] = {};
  const bf16x8* As8 = (const bf16x8*)As;
  const bf16x8* Bs8 = (const bf16x8*)Bs;

  int row = tid & 127, ks = tid >> 7;  // slots tid and tid+256
  const u16* srcA0 = A + (size_t)(m0 + row) * K + ks * 8;
  const u16* srcA1 = A + (size_t)(m0 + row) * K + (ks + 2) * 8;
  const u16* srcB0 = Bm + (size_t)(n0 + row) * K + ks * 8;
  const u16* srcB1 = Bm + (size_t)(n0 + row) * K + (ks + 2) * 8;
  u16* dA0 = &As[(size_t)tid * 8];
  u16* dA1 = &As[(size_t)(tid + 256) * 8];
  u16* dB0 = &Bs[(size_t)tid * 8];
  u16* dB1 = &Bs[(size_t)(tid + 256) * 8];

  for (int t = 0; t < K / 32; ++t) {
    gld16(srcA0 + t * 32, dA0);
    gld16(srcA1 + t * 32, dA1);
    gld16(srcB0 + t * 32, dB0);
    gld16(srcB1 + t * 32, dB1);
    __syncthreads();
    bf16x8 af[4], bfr[4];
#pragma unroll
    for (int m = 0; m < 4; ++m) af[m] = As8[fq * 128 + wr * 64 + m * 16 + fr];
#pragma unroll
    for (int n = 0; n < 4; ++n) bfr[n] = Bs8[fq * 128 + wc * 64 + n * 16 + fr];
#pragma unroll
    for (int m = 0; m < 4; ++m)
#pragma unroll
      for (int n = 0; n < 4; ++n) acc[m][n] = mfma16(af[m], bfr[n], acc[m][n]);
    __syncthreads();
  }

#pragma unroll
  for (int m = 0; m < 4; ++m) {
#pragma unroll
    for (int j = 0; j < 4; ++j) {
      int r = m0 + wr * 64 + m * 16 + fq * 4 + j;
      if (epi == 1) {
        int s = r & (S - 1);
#pragma unroll
        for (int n = 0; n < 2; ++n) {
          int c = n0 + wc * 64 + n * 16 + fr;
          int d1 = c & 63;  // in [0,32)
          float x1 = acc[m][n][j] + bias[c];
          float x2 = acc[m][n + 2][j] + bias[c + 32];
          float invf = exp2f((float)d1 * (-13.287712379549449f / 32.f));
          float ang = (float)s * invf;
          float sn, cs;
          sincosf(ang, &sn, &cs);
          __builtin_nontemporal_store(f2bf(x1 * cs - x2 * sn),
                                      &outb[(size_t)r * N + c]);
          __builtin_nontemporal_store(f2bf(x1 * sn + x2 * cs),
                                      &outb[(size_t)r * N + c + 32]);
        }
      } else if (epi == 0) {
#pragma unroll
        for (int n = 0; n < 4; ++n) {
          int c = n0 + wc * 64 + n * 16 + fr;
          __builtin_nontemporal_store(f2bf(acc[m][n][j] + bias[c]),
                                      &outb[(size_t)r * N + c]);
        }
      } else {
#pragma unroll
        for (int n = 0; n < 4; ++n) {
          int c = n0 + wc * 64 + n * 16 + fr;
          __builtin_nontemporal_store(acc[m][n][j] + bias[c],
                                      &outf[(size_t)r * N + c]);
        }
      }
    }
  }
}

// Fused QKV: 1536 blocks, z = bid>>9 selects tensor.
__global__ __launch_bounds__(256, 3) void gemm_qkv(
    const u16* __restrict__ qb, const u16* __restrict__ kb,
    const u16* __restrict__ vb, const u16* __restrict__ w4,
    const float* __restrict__ bq, const float* __restrict__ bk,
    const float* __restrict__ bv, u16* __restrict__ Qh, u16* __restrict__ Kh,
    u16* __restrict__ Vh) {
  int bid = blockIdx.x;
  int z = bid >> 9, wg = bid & 511;
  const u16* A = z == 0 ? qb : z == 1 ? kb : vb;
  const u16* Bm = w4 + ((size_t)z << 20);
  const float* bias = z == 0 ? bq : z == 1 ? bk : bv;
  u16* C = z == 0 ? Qh : z == 1 ? Kh : Vh;
  gemm_body(A, Bm, bias, C, nullptr, z < 2 ? 1 : 0, wg);
}

__global__ __launch_bounds__(256, 3) void gemm_out(const u16* __restrict__ X,
                                                   const u16* __restrict__ wp,
                                                   const float* __restrict__ bp,
                                                   float* __restrict__ Cf) {
  gemm_body(X, wp, bp, nullptr, Cf, 2, blockIdx.x);
}

// ---------------- V transpose: (B,S,E) -> (B,H,D,S) ----------------
__global__ __launch_bounds__(256) void transpose_v(const u16* __restrict__ Vh,
                                                   u16* __restrict__ Vt) {
  __shared__ u16 t[64][80];
  int bid = blockIdx.x;  // B*H*16
  int s0 = (bid & 15) * 64;
  int bh = bid >> 4;
  int b = bh >> 4, h = bh & 15;
  int tid = threadIdx.x;
  {
    int sl = tid >> 2, d4 = (tid & 3) * 16;
    const uint4* src = (const uint4*)(Vh + (size_t)(b * S + s0 + sl) * E + h * 64 + d4);
    uint4 v0 = src[0], v1 = src[1];
    *(uint4*)&t[sl][d4] = v0;
    *(uint4*)&t[sl][d4 + 8] = v1;
  }
  __syncthreads();
  {
    int dl = tid >> 2, s4 = (tid & 3) * 16;
    u16 tmp[16];
#pragma unroll
    for (int e = 0; e < 16; ++e) tmp[e] = t[s4 + e][dl];
    u16* dst = Vt + (size_t)((b * H + h) * D + dl) * S + s0 + s4;
    *(uint4*)dst = *(const uint4*)tmp;
    *(uint4*)(dst + 8) = *(const uint4*)(tmp + 8);
  }
}

// ---------------- flash attention (swapped-QK^T, 32x32 MFMA) ----------------
// bid = g*64 + qt*8 + (bh&7): q-tiles of one head run concurrently, same XCD.
__global__ __launch_bounds__(256) void attn_fwd(const u16* __restrict__ Qh,
                                                const u16* __restrict__ Kh,
                                                const u16* __restrict__ Vt,
                                                const int* __restrict__ mask,
                                                u16* __restrict__ X) {
  __shared__ u16 Ks[2][8 * 64 * 8];  // [buf][d-chunk][key-slot][8]
  __shared__ u16 Vs[2][8 * 64 * 8];  // [buf][k-chunk][d-slot][8]
  __shared__ float maskb[S];
  constexpr float SC = 0.18033688011112042f;  // 0.125 * log2(e)
  int bid = blockIdx.x;
  int qt = (bid >> 3) & 7;
  int bh = (bid >> 6) * 8 + (bid & 7);
  int b = bh >> 4, h = bh & 15;
  int q0 = qt * 128;
  int tid = threadIdx.x, lane = tid & 63, wid = tid >> 6;
  int hi = lane >> 5, r5 = lane & 31;
  int sw_r5 = r5 ^ ((r5 >> 3) & 3);  // bank-swizzle involution

  const int* mrow = mask + b * S;
  for (int i = tid; i < S; i += 256) maskb[i] = mrow[i] ? 0.f : -1e30f;

  bf16x8 aq[4];
  {
    const u16* qp = Qh + (size_t)(b * S + q0 + wid * 32 + r5) * E + h * 64 + hi * 8;
#pragma unroll
    for (int dc = 0; dc < 4; ++dc) aq[dc] = *(const bf16x8*)(qp + dc * 16);
  }
  f32x16 oacc0 = {}, oacc1 = {};
  float mrun = -INFINITY, lrun = 0.f;

  size_t kbase = (size_t)(b * S) * E + h * 64;
  size_t vbase = (size_t)((b * H + h) * D) * S;
  const bf16x8* Ks8 = (const bf16x8*)Ks;
  const bf16x8* Vs8 = (const bf16x8*)Vs;
  int swl = lane ^ ((lane >> 3) & 3);

  auto stage = [&](int buf, int t) {
    int kv0 = t * 64;
#pragma unroll
    for (int c4 = 0; c4 < 4; ++c4) {
      int ch = wid * 4 + c4;
      if (ch < 8) {
        gld16(Kh + kbase + (size_t)(kv0 + swl) * E + ch * 8, &Ks[buf][ch * 512 + lane * 8]);
      } else {
        int c = ch - 8;
        gld16(Vt + vbase + (size_t)swl * S + kv0 + c * 8, &Vs[buf][c * 512 + lane * 8]);
      }
    }
  };

  stage(0, 0);
  __syncthreads();
  int cur = 0;
  for (int t = 0; t < 16; ++t) {
    if (t < 15) stage(cur ^ 1, t + 1);
    int kv0 = t * 64;

    // ---- S^T = K Q^T ----
    f32x16 p0 = {}, p1 = {};
#pragma unroll
    for (int dc = 0; dc < 4; ++dc) {
      bf16x8 k0 = Ks8[cur * 512 + (dc * 2 + hi) * 64 + sw_r5];
      bf16x8 k1 = Ks8[cur * 512 + (dc * 2 + hi) * 64 + 32 + sw_r5];
      p0 = mfma32(k0, aq[dc], p0);
      p1 = mfma32(k1, aq[dc], p1);
    }

    // ---- scale to log2-domain + mask bias ----
#pragma unroll
    for (int g = 0; g < 4; ++g) {
      f32x4 mb0 = *(const f32x4*)&maskb[kv0 + g * 8 + hi * 4];
      f32x4 mb1 = *(const f32x4*)&maskb[kv0 + 32 + g * 8 + hi * 4];
#pragma unroll
      for (int jj = 0; jj < 4; ++jj) {
        p0[g * 4 + jj] = fmaf(p0[g * 4 + jj], SC, mb0[jj]);
        p1[g * 4 + jj] = fmaf(p1[g * 4 + jj], SC, mb1[jj]);
      }
    }

    // ---- online softmax (base-2), defer-max ----
    float mt = p0[0];
#pragma unroll
    for (int i = 1; i < 16; ++i) mt = fmaxf(mt, p0[i]);
#pragma unroll
    for (int i = 0; i < 16; ++i) mt = fmaxf(mt, p1[i]);
    mt = fmaxf(mt, __shfl_xor(mt, 32));
    if (!__all(mt - mrun <= 8.f)) {
      float mnew = fmaxf(mrun, mt);
      float fac = exp2a(mrun - mnew);
      lrun *= fac;
#pragma unroll
      for (int i = 0; i < 16; ++i) {
        oacc0[i] *= fac;
        oacc1[i] *= fac;
      }
      mrun = mnew;
    }
    float rs = 0.f;
#pragma unroll
    for (int i = 0; i < 16; ++i) {
      p0[i] = exp2a(p0[i] - mrun);
      rs += p0[i];
    }
#pragma unroll
    for (int i = 0; i < 16; ++i) {
      p1[i] = exp2a(p1[i] - mrun);
      rs += p1[i];
    }
    rs += __shfl_xor(rs, 32);
    lrun += rs;

    // ---- P relayout (cvt_pk + permlane32_swap) and PV: O^T = V^T P^T ----
#pragma unroll
    for (int kc = 0; kc < 4; ++kc) {
      int gA = (kc & 1) * 2, gB = gA + 1;
      u32 a0, a1, b0, b1;
      if (kc < 2) {
        a0 = cvtpk_bf16(p0[gA * 4 + 0], p0[gA * 4 + 1]);
        a1 = cvtpk_bf16(p0[gA * 4 + 2], p0[gA * 4 + 3]);
        b0 = cvtpk_bf16(p0[gB * 4 + 0], p0[gB * 4 + 1]);
        b1 = cvtpk_bf16(p0[gB * 4 + 2], p0[gB * 4 + 3]);
      } else {
        a0 = cvtpk_bf16(p1[gA * 4 + 0], p1[gA * 4 + 1]);
        a1 = cvtpk_bf16(p1[gA * 4 + 2], p1[gA * 4 + 3]);
        b0 = cvtpk_bf16(p1[gB * 4 + 0], p1[gB * 4 + 1]);
        b1 = cvtpk_bf16(p1[gB * 4 + 2], p1[gB * 4 + 3]);
      }
      asm volatile("v_permlane32_swap_b32 %0, %1" : "+v"(a0), "+v"(b0));
      asm volatile("v_permlane32_swap_b32 %0, %1" : "+v"(a1), "+v"(b1));
      union {
        u32 w[4];
        bf16x8 v;
      } pu;
      pu.w[0] = a0;
      pu.w[1] = a1;
      pu.w[2] = b0;
      pu.w[3] = b1;
      bf16x8 av0 = Vs8[cur * 512 + (kc * 2 + hi) * 64 + sw_r5];
      bf16x8 av1 = Vs8[cur * 512 + (kc * 2 + hi) * 64 + 32 + sw_r5];
      oacc0 = mfma32(av0, pu.v, oacc0);
      oacc1 = mfma32(av1, pu.v, oacc1);
    }
    __syncthreads();
    cur ^= 1;
  }

  float rl = 1.f / lrun;
  u16* xrow = X + (size_t)(b * S + q0 + wid * 32 + r5) * E + h * 64;
#pragma unroll
  for (int dn = 0; dn < 2; ++dn) {
#pragma unroll
    for (int g = 0; g < 4; ++g) {
#pragma unroll
      for (int m2 = 0; m2 < 2; ++m2) {
        float v0, v1;
        if (dn == 0) {
          v0 = oacc0[g * 4 + m2 * 2] * rl;
          v1 = oacc0[g * 4 + m2 * 2 + 1] * rl;
        } else {
          v0 = oacc1[g * 4 + m2 * 2] * rl;
          v1 = oacc1[g * 4 + m2 * 2 + 1] * rl;
        }
        u16 pr[2] = {f2bf(v0), f2bf(v1)};
        *(u32*)(xrow + dn * 32 + g * 8 + hi * 4 + m2 * 2) = *(const u32*)pr;
      }
    }
  }
}

extern "C" void kernel_launch(void* const* d_in, const int* in_sizes, int n_in,
                              void* d_out, int out_size, void* d_ws, size_t ws_size,
                              hipStream_t stream) {
  const float* q = (const float*)d_in[0];
  const float* k = (const float*)d_in[1];
  const float* v = (const float*)d_in[2];
  const int* mask = (const int*)d_in[3];
  const float* Wq = (const float*)d_in[4];
  const float* bq = (const float*)d_in[5];
  const float* Wk = (const float*)d_in[6];
  const float* bk = (const float*)d_in[7];
  const float* Wv = (const float*)d_in[8];
  const float* bv = (const float*)d_in[9];
  const float* Wp = (const float*)d_in[10];
  const float* bp = (const float*)d_in[11];

  char* ws = (char*)d_ws;
  size_t off = 0;
  auto alloc = [&](size_t bytes) {
    void* p = ws + off;
    off += (bytes + 255) & ~(size_t)255;
    return p;
  };
  u16* qb = (u16*)alloc((size_t)M * E * 2);
  u16* kb = (u16*)alloc((size_t)M * E * 2);
  u16* vb = (u16*)alloc((size_t)M * E * 2);
  u16* w4 = (u16*)alloc((size_t)4 * E * E * 2);
  u16* Qh = (u16*)alloc((size_t)M * E * 2);
  u16* Kh = (u16*)alloc((size_t)M * E * 2);
  u16* Vh = (u16*)alloc((size_t)M * E * 2);
  u16* Vt = qb;  // qb dead after gemm_qkv
  u16* X = kb;   // kb dead after gemm_qkv

  prep_cast<<<2048, 256, 0, stream>>>(q, k, v, Wq, Wk, Wv, Wp, qb, kb, vb, w4);
  gemm_qkv<<<1536, 256, 0, stream>>>(qb, kb, vb, w4, bq, bk, bv, Qh, Kh, Vh);
  transpose_v<<<2048, 256, 0, stream>>>(Vh, Vt);
  attn_fwd<<<1024, 256, 0, stream>>>(Qh, Kh, Vt, mask, X);
  gemm_out<<<512, 256, 0, stream>>>(X, w4 + ((size_t)3 << 20), bp, (float*)d_out);
}